// Round 1
// baseline (198.799 us; speedup 1.0000x reference)
//
#include <hip/hip_runtime.h>
#include <math.h>

#define DD 4096
#define NP 32
#define BB 8
#define NBLK 16   // = DD/256, blocks per batch in chain kernel

// ws layout (floats):
//   Pt      : [32][4096]      = 131072 floats (512 KB)  -- P^T, coalesced per-j reads
//   Qmat    : [B][32][32]     =   8192 floats ( 32 KB)  -- per-batch orthonormal GS basis
//   partial : [B][32][NBLK]   =   4096 floats ( 16 KB)  -- per-block partial sums
// total 573,440 bytes

// --- Kernel 1: pack P^T so the chain kernel's p_d loads are coalesced ---
__global__ __launch_bounds__(256) void pack_pt(const float* __restrict__ eig,
                                               float* __restrict__ Pt) {
    int d = blockIdx.x * 256 + threadIdx.x;
    const float4* row = (const float4*)(eig + (size_t)d * DD);
    float4 r[8];
#pragma unroll
    for (int i = 0; i < 8; i++) r[i] = row[i];
#pragma unroll
    for (int i = 0; i < 8; i++) {
        Pt[(size_t)(i * 4 + 0) * DD + d] = r[i].x;
        Pt[(size_t)(i * 4 + 1) * DD + d] = r[i].y;
        Pt[(size_t)(i * 4 + 2) * DD + d] = r[i].z;
        Pt[(size_t)(i * 4 + 3) * DD + d] = r[i].w;
    }
}

// --- Kernel 2: per-batch modified Gram-Schmidt on the 32 selected rows ---
// One wave per batch; lanes 0-31 hold the 32 components (lanes 32-63 mirror).
__global__ __launch_bounds__(64) void gs_kernel(const float* __restrict__ eig,
                                                const int* __restrict__ pos,
                                                float* __restrict__ Qmat) {
    int b = blockIdx.x;
    int tid = threadIdx.x;
    int lane = tid & 31;
    __shared__ float Q[NP][32];
    __shared__ int ps[NP];
    if (tid < NP) ps[tid] = pos[b * NP + tid];
    __syncthreads();
    for (int k = 0; k < NP; k++) {
        float r = eig[(size_t)ps[k] * DD + lane];  // p_{pos_k}[lane]
        for (int j = 0; j < k; j++) {
            float qj = Q[j][lane];
            float c = qj * r;
            c += __shfl_xor(c, 1, 32); c += __shfl_xor(c, 2, 32);
            c += __shfl_xor(c, 4, 32); c += __shfl_xor(c, 8, 32);
            c += __shfl_xor(c, 16, 32);
            r -= c * qj;   // modified GS: project out q_j sequentially
        }
        float n2 = r * r;
        n2 += __shfl_xor(n2, 1, 32); n2 += __shfl_xor(n2, 2, 32);
        n2 += __shfl_xor(n2, 4, 32); n2 += __shfl_xor(n2, 8, 32);
        n2 += __shfl_xor(n2, 16, 32);
        float inv = 1.0f / sqrtf(n2);
        if (tid < NP) Q[k][lane] = r * inv;
        __syncthreads();
    }
    for (int i = tid; i < NP * 32; i += 64) Qmat[b * NP * 32 + i] = ((float*)Q)[i];
}

// --- Kernel 3: the fully-parallel per-(b,d) chain evaluation ---
// unnorm_k[d] = ||p_d||^2 - sum_{j<k} t_j^2,  t_j = q_j . p_d
// s_k[d]      = sum_{j<k} v[pos_j, d]          (v symmetric -> row read, coalesced)
// out = |unnorm/(N-k)| * exp(-0.5 s)  (unnormalized; normalized in kernel 4)
__global__ __launch_bounds__(256) void chain_kernel(const float* __restrict__ Pt,
                                                    const float* __restrict__ v,
                                                    const int* __restrict__ pos,
                                                    const float* __restrict__ Qmat,
                                                    float* __restrict__ out,
                                                    float* __restrict__ partial) {
    int b = blockIdx.y;
    int tid = threadIdx.x;
    int d = blockIdx.x * 256 + tid;
    __shared__ float Q[NP][32];
    __shared__ int ps[NP];
    __shared__ float wsum[4][NP];
    if (tid < NP) ps[tid] = pos[b * NP + tid];
    for (int i = tid; i < NP * 32; i += 256) ((float*)Q)[i] = Qmat[b * NP * 32 + i];
    __syncthreads();

    float p[32];
#pragma unroll
    for (int j = 0; j < 32; j++) p[j] = Pt[(size_t)j * DD + d];
    float diagU = 0.f;
#pragma unroll
    for (int j = 0; j < 32; j++) diagU += p[j] * p[j];

    float t[NP];
#pragma unroll
    for (int k = 0; k < NP; k++) {
        const float4* q4 = (const float4*)(&Q[k][0]);  // broadcast reads
        float acc = 0.f;
#pragma unroll
        for (int i = 0; i < 8; i++) {
            float4 qq = q4[i];
            acc += qq.x * p[4 * i] + qq.y * p[4 * i + 1]
                 + qq.z * p[4 * i + 2] + qq.w * p[4 * i + 3];
        }
        t[k] = acc;
    }

    float un = diagU, s = 0.f;
    int wid = tid >> 6;
#pragma unroll
    for (int k = 0; k < NP; k++) {
        float pr = fabsf(un * (1.0f / (NP - k))) * expf(-0.5f * s);
        out[((size_t)(b * NP + k)) * DD + d] = pr;
        float r = pr;  // wave reduce (64 lanes) for deterministic partial sums
        r += __shfl_xor(r, 1);  r += __shfl_xor(r, 2);  r += __shfl_xor(r, 4);
        r += __shfl_xor(r, 8);  r += __shfl_xor(r, 16); r += __shfl_xor(r, 32);
        if ((tid & 63) == 0) wsum[wid][k] = r;
        s += v[(size_t)ps[k] * DD + d];
        un -= t[k] * t[k];
    }
    __syncthreads();
    if (tid < NP) {
        float sb = wsum[0][tid] + wsum[1][tid] + wsum[2][tid] + wsum[3][tid];
        partial[(size_t)(b * NP + tid) * NBLK + blockIdx.x] = sb;
    }
}

// --- Kernel 4: deterministic normalization out[b,k,:] /= sum ---
__global__ __launch_bounds__(256) void norm_kernel(float* __restrict__ out,
                                                   const float* __restrict__ partial) {
    int bk = blockIdx.x;  // 0..B*NP-1
    __shared__ float invs;
    if (threadIdx.x == 0) {
        float s = 0.f;
        for (int i = 0; i < NBLK; i++) s += partial[bk * NBLK + i];
        invs = 1.0f / s;
    }
    __syncthreads();
    float iv = invs;
    float4* o = (float4*)(out + (size_t)bk * DD);
    for (int i = threadIdx.x; i < DD / 4; i += 256) {
        float4 x = o[i];
        x.x *= iv; x.y *= iv; x.z *= iv; x.w *= iv;
        o[i] = x;
    }
}

extern "C" void kernel_launch(void* const* d_in, const int* in_sizes, int n_in,
                              void* d_out, int out_size, void* d_ws, size_t ws_size,
                              hipStream_t stream) {
    const float* eig = (const float*)d_in[0];   // (4096,4096) f32
    const float* v   = (const float*)d_in[1];   // (4096,4096) f32, symmetric
    const int*  pos  = (const int*)d_in[2];     // (8,32) i32
    float* out = (float*)d_out;                 // (8,32,4096) f32
    float* ws  = (float*)d_ws;
    float* Pt      = ws;                        // 32*4096
    float* Qmat    = Pt + 32 * DD;              // 8*32*32
    float* partial = Qmat + BB * NP * 32;       // 8*32*NBLK

    pack_pt<<<dim3(DD / 256), 256, 0, stream>>>(eig, Pt);
    gs_kernel<<<dim3(BB), 64, 0, stream>>>(eig, pos, Qmat);
    chain_kernel<<<dim3(NBLK, BB), 256, 0, stream>>>(Pt, v, pos, Qmat, out, partial);
    norm_kernel<<<dim3(BB * NP), 256, 0, stream>>>(out, partial);
}

// Round 2
// 186.846 us; speedup vs baseline: 1.0640x; 1.0640x over previous
//
#include <hip/hip_runtime.h>
#include <math.h>

#define DD 4096
#define NP 32
#define BB 8
#define NBLK 16   // = DD/256, blocks per batch in chain kernel

// ws layout (floats):
//   Pt      : [32][4096]      = 131072 floats (512 KB)  -- P^T, coalesced per-j reads
//   Qmat    : [B][32][32]     =   8192 floats ( 32 KB)  -- per-batch orthonormal GS basis
//   partial : [B][32][NBLK]   =   4096 floats ( 16 KB)  -- per-block partial sums

// --- Kernel 1: pack P^T so the chain kernel's p_d loads are coalesced ---
__global__ __launch_bounds__(256) void pack_pt(const float* __restrict__ eig,
                                               float* __restrict__ Pt) {
    int d = blockIdx.x * 256 + threadIdx.x;
    const float4* row = (const float4*)(eig + (size_t)d * DD);
    float4 r[8];
#pragma unroll
    for (int i = 0; i < 8; i++) r[i] = row[i];
#pragma unroll
    for (int i = 0; i < 8; i++) {
        Pt[(size_t)(i * 4 + 0) * DD + d] = r[i].x;
        Pt[(size_t)(i * 4 + 1) * DD + d] = r[i].y;
        Pt[(size_t)(i * 4 + 2) * DD + d] = r[i].z;
        Pt[(size_t)(i * 4 + 3) * DD + d] = r[i].w;
    }
}

// --- Kernel 2: per-batch CGS2 Gram-Schmidt on the 32 selected rows ---
// One wave (64 threads) per batch. All 32 rows live in LDS; per step k:
//   pass x2 (reorthogonalization):
//     lane j: c_j = Q[j].Q[k] serially in-lane (no cross-lane reduce)
//     lane i: Q[k][i] -= sum_j shfl(c,j) * Q[j][i]
//   then one 5-step shuffle reduce for the norm (32 total, off critical path).
__global__ __launch_bounds__(64) void gs_kernel(const float* __restrict__ eig,
                                                const int* __restrict__ pos,
                                                float* __restrict__ Qmat) {
    int b = blockIdx.x;
    int tid = threadIdx.x;
    int lane = tid & 31;
    __shared__ float Q[NP][34];   // pad 34: float2 reads 2-way-max (free) banks
    __shared__ int ps[NP];
    if (tid < NP) ps[tid] = pos[b * NP + tid];
    __syncthreads();
    // coalesced preload of A = eig[ps[:], 0:32] (2 rows per iteration)
    for (int k = (tid >> 5); k < NP; k += 2)
        Q[k][lane] = eig[(size_t)ps[k] * DD + lane];
    __syncthreads();

    for (int k = 0; k < NP; k++) {
#pragma unroll
        for (int rep = 0; rep < 2; rep++) {
            const float2* qj = (const float2*)&Q[lane][0];
            const float2* qk = (const float2*)&Q[k][0];
            float a0 = 0.f, a1 = 0.f;
#pragma unroll
            for (int i = 0; i < 16; i += 2) {
                float2 x0 = qj[i],     y0 = qk[i];
                float2 x1 = qj[i + 1], y1 = qk[i + 1];
                a0 += x0.x * y0.x + x0.y * y0.y;
                a1 += x1.x * y1.x + x1.y * y1.y;
            }
            float c = (lane < k) ? (a0 + a1) : 0.f;  // zero-pad: full unroll below
            float acc0 = 0.f, acc1 = 0.f;
#pragma unroll
            for (int j = 0; j < NP; j += 2) {
                acc0 += __shfl(c, j)     * Q[j][lane];
                acc1 += __shfl(c, j + 1) * Q[j + 1][lane];
            }
            __syncthreads();
            Q[k][lane] -= acc0 + acc1;
            __syncthreads();
        }
        float val = Q[k][lane];
        float n2 = val * val;
        n2 += __shfl_xor(n2, 1);  n2 += __shfl_xor(n2, 2);
        n2 += __shfl_xor(n2, 4);  n2 += __shfl_xor(n2, 8);
        n2 += __shfl_xor(n2, 16);
        float inv = 1.0f / sqrtf(n2);
        Q[k][lane] = val * inv;
        __syncthreads();
    }
    for (int i = tid; i < NP * 32; i += 64)
        Qmat[b * NP * 32 + i] = Q[i >> 5][i & 31];
}

// --- Kernel 3: the fully-parallel per-(b,d) chain evaluation ---
// unnorm_k[d] = ||p_d||^2 - sum_{j<k} t_j^2,  t_j = q_j . p_d
// s_k[d]      = sum_{j<k} v[pos_j, d]          (v symmetric -> row read, coalesced)
__global__ __launch_bounds__(256) void chain_kernel(const float* __restrict__ Pt,
                                                    const float* __restrict__ v,
                                                    const int* __restrict__ pos,
                                                    const float* __restrict__ Qmat,
                                                    float* __restrict__ out,
                                                    float* __restrict__ partial) {
    int b = blockIdx.y;
    int tid = threadIdx.x;
    int d = blockIdx.x * 256 + tid;
    __shared__ float Q[NP][32];
    __shared__ int ps[NP];
    __shared__ float wsum[4][NP];
    if (tid < NP) ps[tid] = pos[b * NP + tid];
    for (int i = tid; i < NP * 32; i += 256) ((float*)Q)[i] = Qmat[b * NP * 32 + i];
    __syncthreads();

    float p[32];
#pragma unroll
    for (int j = 0; j < 32; j++) p[j] = Pt[(size_t)j * DD + d];
    float diagU = 0.f;
#pragma unroll
    for (int j = 0; j < 32; j++) diagU += p[j] * p[j];

    float t[NP];
#pragma unroll
    for (int k = 0; k < NP; k++) {
        const float4* q4 = (const float4*)(&Q[k][0]);  // broadcast reads
        float acc = 0.f;
#pragma unroll
        for (int i = 0; i < 8; i++) {
            float4 qq = q4[i];
            acc += qq.x * p[4 * i] + qq.y * p[4 * i + 1]
                 + qq.z * p[4 * i + 2] + qq.w * p[4 * i + 3];
        }
        t[k] = acc;
    }

    float un = diagU, s = 0.f;
    int wid = tid >> 6;
#pragma unroll
    for (int k = 0; k < NP; k++) {
        float pr = fabsf(un * (1.0f / (NP - k))) * expf(-0.5f * s);
        out[((size_t)(b * NP + k)) * DD + d] = pr;
        float r = pr;  // wave reduce (64 lanes) for deterministic partial sums
        r += __shfl_xor(r, 1);  r += __shfl_xor(r, 2);  r += __shfl_xor(r, 4);
        r += __shfl_xor(r, 8);  r += __shfl_xor(r, 16); r += __shfl_xor(r, 32);
        if ((tid & 63) == 0) wsum[wid][k] = r;
        s += v[(size_t)ps[k] * DD + d];
        un -= t[k] * t[k];
    }
    __syncthreads();
    if (tid < NP) {
        float sb = wsum[0][tid] + wsum[1][tid] + wsum[2][tid] + wsum[3][tid];
        partial[(size_t)(b * NP + tid) * NBLK + blockIdx.x] = sb;
    }
}

// --- Kernel 4: deterministic normalization out[b,k,:] /= sum ---
__global__ __launch_bounds__(256) void norm_kernel(float* __restrict__ out,
                                                   const float* __restrict__ partial) {
    int bk = blockIdx.x;  // 0..B*NP-1
    __shared__ float invs;
    if (threadIdx.x == 0) {
        float s = 0.f;
        for (int i = 0; i < NBLK; i++) s += partial[bk * NBLK + i];
        invs = 1.0f / s;
    }
    __syncthreads();
    float iv = invs;
    float4* o = (float4*)(out + (size_t)bk * DD);
    for (int i = threadIdx.x; i < DD / 4; i += 256) {
        float4 x = o[i];
        x.x *= iv; x.y *= iv; x.z *= iv; x.w *= iv;
        o[i] = x;
    }
}

extern "C" void kernel_launch(void* const* d_in, const int* in_sizes, int n_in,
                              void* d_out, int out_size, void* d_ws, size_t ws_size,
                              hipStream_t stream) {
    const float* eig = (const float*)d_in[0];   // (4096,4096) f32
    const float* v   = (const float*)d_in[1];   // (4096,4096) f32, symmetric
    const int*  pos  = (const int*)d_in[2];     // (8,32) i32
    float* out = (float*)d_out;                 // (8,32,4096) f32
    float* ws  = (float*)d_ws;
    float* Pt      = ws;                        // 32*4096
    float* Qmat    = Pt + 32 * DD;              // 8*32*32
    float* partial = Qmat + BB * NP * 32;       // 8*32*NBLK

    pack_pt<<<dim3(DD / 256), 256, 0, stream>>>(eig, Pt);
    gs_kernel<<<dim3(BB), 64, 0, stream>>>(eig, pos, Qmat);
    chain_kernel<<<dim3(NBLK, BB), 256, 0, stream>>>(Pt, v, pos, Qmat, out, partial);
    norm_kernel<<<dim3(BB * NP), 256, 0, stream>>>(out, partial);
}

// Round 4
// 43.389 us; speedup vs baseline: 4.5817x; 4.3063x over previous
//
#include <hip/hip_runtime.h>
#include <math.h>

#define DD 4096
#define NP 32
#define BB 8
#define NBLK 16   // blocks per batch; grid = (NBLK, BB), 256 threads

// ws layout (floats): partial[B][NP][NBLK] = 4096 floats

// --- Fused kernel: register-GS + per-(b,d) chain evaluation ---
// Math: unnorm_k[d] = ||p_d||^2 - sum_{j<k} (q_j . p_d)^2   (q = GS of selected rows)
//       s_k[d]      = sum_{j<k} v[ps_j, d]   (v symmetric -> coalesced row reads)
//       out[b,k,d]  = |unnorm_k/(NP-k)| * exp(-0.5 s_k)   (normalized in kernel 2)
__global__ __launch_bounds__(256, 1) void fused_kernel(const float* __restrict__ eig,
                                                       const float* __restrict__ v,
                                                       const int* __restrict__ pos,
                                                       float* __restrict__ out,
                                                       float* __restrict__ partial) {
    const int b = blockIdx.y;
    const int tid = threadIdx.x;
    const int d = blockIdx.x * 256 + tid;
    const int lane = tid & 63;
    const int wid = tid >> 6;
    const int r = lane & 31;          // GS row owned by this lane (lanes 32-63 mirror)

    __shared__ int ps[NP];
    __shared__ float Q[NP][36];       // 36: keeps float4 rows 16B-aligned, broadcast reads conflict-free
    __shared__ float wsum[4][NP];

    if (tid < NP) ps[tid] = pos[b * NP + tid];
    __syncthreads();

    // ---- issue v loads early: latency hides under register-GS compute ----
    float vv[NP];
#pragma unroll
    for (int k = 0; k < NP; k++) vv[k] = v[(size_t)ps[k] * DD + d];

    // ---- GS input: lane r holds row ps[r] of P (32 floats, 8x float4 = 128B contiguous) ----
    float a[NP];
    {
        const float4* arow = (const float4*)(eig + (size_t)ps[r] * DD);
#pragma unroll
        for (int i = 0; i < 8; i++) {
            float4 t = arow[i];
            a[4 * i] = t.x; a[4 * i + 1] = t.y; a[4 * i + 2] = t.z; a[4 * i + 3] = t.w;
        }
    }

    // ---- right-looking MGS, fully in registers, no LDS/barriers ----
    for (int k = 0; k < NP; k++) {
        float rk[NP];
#pragma unroll
        for (int i = 0; i < NP; i++) rk[i] = __shfl(a[i], k);   // independent, pipelined
        float n0 = 0.f, n1 = 0.f;                               // redundant per-lane norm (no reduce)
#pragma unroll
        for (int i = 0; i < NP; i += 2) { n0 += rk[i] * rk[i]; n1 += rk[i + 1] * rk[i + 1]; }
        float inv = 1.0f / sqrtf(n0 + n1);
#pragma unroll
        for (int i = 0; i < NP; i++) rk[i] *= inv;
        float d0 = 0.f, d1 = 0.f;                               // d_r = q_k . row_r, in-lane
#pragma unroll
        for (int i = 0; i < NP; i += 2) { d0 += a[i] * rk[i]; d1 += a[i + 1] * rk[i + 1]; }
        float f = (r > k) ? (d0 + d1) : 0.f;
#pragma unroll
        for (int i = 0; i < NP; i++) a[i] = (r == k) ? rk[i] : (a[i] - f * rk[i]);
    }

    // ---- p_d loads (latency covered by prefix/exp phase below) ----
    float p[NP];
    {
        const float4* prow = (const float4*)(eig + (size_t)d * DD);
#pragma unroll
        for (int i = 0; i < 8; i++) {
            float4 t = prow[i];
            p[4 * i] = t.x; p[4 * i + 1] = t.y; p[4 * i + 2] = t.z; p[4 * i + 3] = t.w;
        }
    }

    // ---- Jastrow prefix: e[k] = exp(-0.5 * sum_{j<k} vv[j]) ----
    float e[NP];
    {
        float s = 0.f;
#pragma unroll
        for (int k = 0; k < NP; k++) { e[k] = expf(-0.5f * s); s += vv[k]; }
    }

    float diagU = 0.f;
#pragma unroll
    for (int j = 0; j < NP; j++) diagU += p[j] * p[j];

    // ---- deposit Q (wave 0 only; identical in all waves) ----
    if (wid == 0 && lane < NP) {
        float4* qr = (float4*)&Q[lane][0];
#pragma unroll
        for (int i = 0; i < 8; i++) qr[i] = make_float4(a[4 * i], a[4 * i + 1], a[4 * i + 2], a[4 * i + 3]);
    }
    __syncthreads();

    // ---- 32-step probability chain (fully unrolled: e[k] must be reg-indexed) ----
    float un = diagU;
#pragma unroll
    for (int k = 0; k < NP; k++) {
        float pr = fabsf(un) * (1.0f / (NP - k)) * e[k];
        out[((size_t)(b * NP + k)) * DD + d] = pr;
        float red = pr;                       // deterministic wave-64 reduction
        red += __shfl_xor(red, 1);  red += __shfl_xor(red, 2);  red += __shfl_xor(red, 4);
        red += __shfl_xor(red, 8);  red += __shfl_xor(red, 16); red += __shfl_xor(red, 32);
        if (lane == 0) wsum[wid][k] = red;
        const float4* q4 = (const float4*)&Q[k][0];   // broadcast reads: conflict-free
        float acc0 = 0.f, acc1 = 0.f;
#pragma unroll
        for (int i = 0; i < 8; i += 2) {
            float4 qa = q4[i], qb = q4[i + 1];
            acc0 += qa.x * p[4 * i] + qa.y * p[4 * i + 1] + qa.z * p[4 * i + 2] + qa.w * p[4 * i + 3];
            acc1 += qb.x * p[4 * i + 4] + qb.y * p[4 * i + 5] + qb.z * p[4 * i + 6] + qb.w * p[4 * i + 7];
        }
        float t = acc0 + acc1;
        un -= t * t;
    }
    __syncthreads();
    if (tid < NP) {
        float sb = wsum[0][tid] + wsum[1][tid] + wsum[2][tid] + wsum[3][tid];
        partial[(size_t)(b * NP + tid) * NBLK + blockIdx.x] = sb;
    }
}

// --- Kernel 2: deterministic normalization out[b,k,:] /= sum ---
__global__ __launch_bounds__(256) void norm_kernel(float* __restrict__ out,
                                                   const float* __restrict__ partial) {
    int bk = blockIdx.x;  // 0..B*NP-1
    __shared__ float invs;
    if (threadIdx.x == 0) {
        float s = 0.f;
        for (int i = 0; i < NBLK; i++) s += partial[bk * NBLK + i];
        invs = 1.0f / s;
    }
    __syncthreads();
    float iv = invs;
    float4* o = (float4*)(out + (size_t)bk * DD);
    for (int i = threadIdx.x; i < DD / 4; i += 256) {
        float4 x = o[i];
        x.x *= iv; x.y *= iv; x.z *= iv; x.w *= iv;
        o[i] = x;
    }
}

extern "C" void kernel_launch(void* const* d_in, const int* in_sizes, int n_in,
                              void* d_out, int out_size, void* d_ws, size_t ws_size,
                              hipStream_t stream) {
    const float* eig = (const float*)d_in[0];   // (4096,4096) f32
    const float* v   = (const float*)d_in[1];   // (4096,4096) f32, symmetric
    const int*  pos  = (const int*)d_in[2];     // (8,32) i32
    float* out = (float*)d_out;                 // (8,32,4096) f32
    float* partial = (float*)d_ws;              // 8*32*NBLK floats

    fused_kernel<<<dim3(NBLK, BB), 256, 0, stream>>>(eig, v, pos, out, partial);
    norm_kernel<<<dim3(BB * NP), 256, 0, stream>>>(out, partial);
}

// Round 5
// 41.963 us; speedup vs baseline: 4.7375x; 1.0340x over previous
//
#include <hip/hip_runtime.h>
#include <math.h>

#define DD 4096
#define NP 32
#define BB 8
#define BT 128            // chain block threads
#define NBLK 32           // DD / BT blocks per batch

// ws layout (floats): Qws[B][32][32] = 8192 ; partial[B][32][NBLK] = 8192

// --- Kernel 1: per-batch register MGS (validated in rounds 2/4), Q -> ws ---
__global__ __launch_bounds__(64) void gs_kernel(const float* __restrict__ eig,
                                                const int* __restrict__ pos,
                                                float* __restrict__ Qws) {
    const int b = blockIdx.x;
    const int tid = threadIdx.x;
    const int r = tid & 31;
    __shared__ int ps[NP];
    if (tid < NP) ps[tid] = pos[b * NP + tid];
    __syncthreads();
    float a[NP];
    {
        const float4* arow = (const float4*)(eig + (size_t)ps[r] * DD);
#pragma unroll
        for (int i = 0; i < 8; i++) {
            float4 t = arow[i];
            a[4 * i] = t.x; a[4 * i + 1] = t.y; a[4 * i + 2] = t.z; a[4 * i + 3] = t.w;
        }
    }
    for (int k = 0; k < NP; k++) {
        float rk[NP];
#pragma unroll
        for (int i = 0; i < NP; i++) rk[i] = __shfl(a[i], k);   // broadcast row k
        float n0 = 0.f, n1 = 0.f;
#pragma unroll
        for (int i = 0; i < NP; i += 2) { n0 += rk[i] * rk[i]; n1 += rk[i + 1] * rk[i + 1]; }
        float inv = 1.0f / sqrtf(n0 + n1);
#pragma unroll
        for (int i = 0; i < NP; i++) rk[i] *= inv;
        float d0 = 0.f, d1 = 0.f;
#pragma unroll
        for (int i = 0; i < NP; i += 2) { d0 += a[i] * rk[i]; d1 += a[i + 1] * rk[i + 1]; }
        float f = (r > k) ? (d0 + d1) : 0.f;
#pragma unroll
        for (int i = 0; i < NP; i++) a[i] = (r == k) ? rk[i] : (a[i] - f * rk[i]);
    }
    if (tid < NP) {
        float4* q = (float4*)(Qws + ((size_t)b * NP + r) * NP);
#pragma unroll
        for (int i = 0; i < 8; i++)
            q[i] = make_float4(a[4 * i], a[4 * i + 1], a[4 * i + 2], a[4 * i + 3]);
    }
}

// --- Kernel 2: per-(b,d) chain, phase-separated (dots -> prefix -> stores -> reduces) ---
__global__ __launch_bounds__(BT, 1) void chain_kernel(const float* __restrict__ eig,
                                                      const float* __restrict__ v,
                                                      const int* __restrict__ pos,
                                                      const float* __restrict__ Qws,
                                                      float* __restrict__ out,
                                                      float* __restrict__ partial) {
    const int b = blockIdx.y;
    const int tid = threadIdx.x;
    const int d = blockIdx.x * BT + tid;
    const int lane = tid & 63;
    const int wid = tid >> 6;
    __shared__ float Q[NP][NP];
    __shared__ int ps[NP];
    __shared__ float wsum[BT / 64][NP];
    if (tid < NP) ps[tid] = pos[b * NP + tid];
    {   // Q: 1024 floats = 256 float4, 128 threads x2
        const float4* src = (const float4*)(Qws + (size_t)b * NP * NP);
        float4* dst = (float4*)&Q[0][0];
        dst[tid] = src[tid];
        dst[tid + BT] = src[tid + BT];
    }
    __syncthreads();

    float p[NP];
    {
        const float4* prow = (const float4*)(eig + (size_t)d * DD);
#pragma unroll
        for (int i = 0; i < 8; i++) {
            float4 t = prow[i];
            p[4 * i] = t.x; p[4 * i + 1] = t.y; p[4 * i + 2] = t.z; p[4 * i + 3] = t.w;
        }
    }
    float vv[NP];
#pragma unroll
    for (int k = 0; k < NP; k++) vv[k] = v[(size_t)ps[k] * DD + d];
    float e[NP];
    {
        float s = 0.f;
#pragma unroll
        for (int k = 0; k < NP; k++) { e[k] = expf(-0.5f * s); s += vv[k]; }
    }
    float diagU = 0.f;
#pragma unroll
    for (int j = 0; j < NP; j++) diagU += p[j] * p[j];

    // ---- all 32 dots, independent (broadcast LDS reads, deep ILP) ----
    float t[NP];
#pragma unroll
    for (int k = 0; k < NP; k++) {
        const float4* q4 = (const float4*)&Q[k][0];
        float a0 = 0.f, a1 = 0.f;
#pragma unroll
        for (int i = 0; i < 8; i += 2) {
            float4 qa = q4[i], qb = q4[i + 1];
            a0 += qa.x * p[4 * i]     + qa.y * p[4 * i + 1] + qa.z * p[4 * i + 2] + qa.w * p[4 * i + 3];
            a1 += qb.x * p[4 * i + 4] + qb.y * p[4 * i + 5] + qb.z * p[4 * i + 6] + qb.w * p[4 * i + 7];
        }
        t[k] = a0 + a1;
    }
    // ---- prefix chain: 1 FMA/step ----
    float pr[NP];
    float un = diagU;
#pragma unroll
    for (int k = 0; k < NP; k++) {
        pr[k] = fabsf(un) * (1.0f / (NP - k)) * e[k];
        un -= t[k] * t[k];
    }
    // ---- stores (coalesced 4B/lane per k-plane) ----
#pragma unroll
    for (int k = 0; k < NP; k++) out[((size_t)(b * NP + k)) * DD + d] = pr[k];
    // ---- 32 independent wave reductions, pipelined ----
#pragma unroll
    for (int k = 0; k < NP; k++) {
        float red = pr[k];
        red += __shfl_xor(red, 1);  red += __shfl_xor(red, 2);  red += __shfl_xor(red, 4);
        red += __shfl_xor(red, 8);  red += __shfl_xor(red, 16); red += __shfl_xor(red, 32);
        if (lane == 0) wsum[wid][k] = red;
    }
    __syncthreads();
    if (tid < NP)
        partial[((size_t)(b * NP + tid)) * NBLK + blockIdx.x] = wsum[0][tid] + wsum[1][tid];
}

// --- Kernel 3: deterministic normalization, lane-parallel sum ---
__global__ __launch_bounds__(256) void norm_kernel(float* __restrict__ out,
                                                   const float* __restrict__ partial) {
    const int bk = blockIdx.x;  // 0..B*NP-1
    __shared__ float invs;
    if (threadIdx.x < 64) {
        float s = (threadIdx.x < NBLK) ? partial[(size_t)bk * NBLK + threadIdx.x] : 0.f;
        s += __shfl_xor(s, 1);  s += __shfl_xor(s, 2);  s += __shfl_xor(s, 4);
        s += __shfl_xor(s, 8);  s += __shfl_xor(s, 16); s += __shfl_xor(s, 32);
        if (threadIdx.x == 0) invs = 1.0f / s;
    }
    __syncthreads();
    const float iv = invs;
    float4* o = (float4*)(out + (size_t)bk * DD);
#pragma unroll
    for (int i = threadIdx.x; i < DD / 4; i += 256) {
        float4 x = o[i];
        x.x *= iv; x.y *= iv; x.z *= iv; x.w *= iv;
        o[i] = x;
    }
}

extern "C" void kernel_launch(void* const* d_in, const int* in_sizes, int n_in,
                              void* d_out, int out_size, void* d_ws, size_t ws_size,
                              hipStream_t stream) {
    const float* eig = (const float*)d_in[0];   // (4096,4096) f32
    const float* v   = (const float*)d_in[1];   // (4096,4096) f32, symmetric
    const int*  pos  = (const int*)d_in[2];     // (8,32) i32
    float* out = (float*)d_out;                 // (8,32,4096) f32
    float* ws  = (float*)d_ws;
    float* Qws     = ws;                        // 8*32*32
    float* partial = Qws + BB * NP * NP;        // 8*32*NBLK

    gs_kernel<<<dim3(BB), 64, 0, stream>>>(eig, pos, Qws);
    chain_kernel<<<dim3(NBLK, BB), BT, 0, stream>>>(eig, v, pos, Qws, out, partial);
    norm_kernel<<<dim3(BB * NP), 256, 0, stream>>>(out, partial);
}